// Round 1
// baseline (7203.543 us; speedup 1.0000x reference)
//
#include <hip/hip_runtime.h>
#include <math.h>

typedef __bf16 bf16x8 __attribute__((ext_vector_type(8)));
typedef float f32x4 __attribute__((ext_vector_type(4)));
typedef unsigned short u16;

__device__ __forceinline__ u16 f2bf(float f) {
  union { float f; unsigned u; } v; v.f = f;
  return (u16)((v.u + 0x7fffu + ((v.u >> 16) & 1u)) >> 16);
}

// C[M,N] = A[M,K] * Bt[N,K]^T (+ epilogue). 128x128 tile, BK=32, 256 thr = 4 waves (2x2 of 64x64).
// EPI: 0 = none, 1 = acc + aux[row,col], 2 = silu(aux[row,col]) * acc
// CSKIP: skip blocks strictly above the diagonal (causal QK^T)
template<int EPI, bool CSKIP>
__global__ __launch_bounds__(256, 2)
void gemm_bt(const float* __restrict__ A, const float* __restrict__ Bt,
             float* __restrict__ C, const float* __restrict__ aux,
             int K, int lda, int ldb, int ldc,
             long long sA, long long sB, long long sC)
{
  if (CSKIP && blockIdx.x > blockIdx.y) return;
  A  += (long long)blockIdx.z * sA;
  Bt += (long long)blockIdx.z * sB;
  C  += (long long)blockIdx.z * sC;
  const int m0 = blockIdx.y * 128, n0 = blockIdx.x * 128;

  __shared__ u16 As[128][40];  // 32 cols + 8 pad, row stride 80 B (16B-aligned, 2-way bank alias = free)
  __shared__ u16 Bs[128][40];

  const int t = threadIdx.x;
  const int l = t & 63;
  const int w = t >> 6;
  const int wm = (w >> 1) * 64, wn = (w & 1) * 64;
  const int frow = l & 15;          // m (A) / n (B) index within 16x16 frag
  const int koff = (l >> 4) * 8;    // k offset: 8 contiguous bf16 per lane

  f32x4 acc[4][4] = {};

  for (int kt = 0; kt < K; kt += 32) {
    // stage A,B tiles: 128x32 fp32 each -> convert -> bf16 LDS. 1024 float4/tile, 4 per thread.
#pragma unroll
    for (int i = 0; i < 4; ++i) {
      int f = t + i * 256;
      int row = f >> 3;
      int c = (f & 7) * 4;
      float4 a4 = *(const float4*)(A + (long long)(m0 + row) * lda + kt + c);
      ushort4 ap; ap.x = f2bf(a4.x); ap.y = f2bf(a4.y); ap.z = f2bf(a4.z); ap.w = f2bf(a4.w);
      *(ushort4*)&As[row][c] = ap;
      float4 b4 = *(const float4*)(Bt + (long long)(n0 + row) * ldb + kt + c);
      ushort4 bp; bp.x = f2bf(b4.x); bp.y = f2bf(b4.y); bp.z = f2bf(b4.z); bp.w = f2bf(b4.w);
      *(ushort4*)&Bs[row][c] = bp;
    }
    __syncthreads();
    bf16x8 af[4], bv[4];
#pragma unroll
    for (int i = 0; i < 4; ++i) af[i] = *(const bf16x8*)&As[wm + i * 16 + frow][koff];
#pragma unroll
    for (int j = 0; j < 4; ++j) bv[j] = *(const bf16x8*)&Bs[wn + j * 16 + frow][koff];
#pragma unroll
    for (int i = 0; i < 4; ++i)
#pragma unroll
      for (int j = 0; j < 4; ++j)
        acc[i][j] = __builtin_amdgcn_mfma_f32_16x16x32_bf16(af[i], bv[j], acc[i][j], 0, 0, 0);
    __syncthreads();
  }

  // C/D layout (m89/m91): col = lane&15, row = (lane>>4)*4 + reg
  const int r0 = (l >> 4) * 4;
  const int cc = l & 15;
#pragma unroll
  for (int i = 0; i < 4; ++i) {
#pragma unroll
    for (int j = 0; j < 4; ++j) {
#pragma unroll
      for (int r = 0; r < 4; ++r) {
        int row = m0 + wm + i * 16 + r0 + r;
        int col = n0 + wn + j * 16 + cc;
        float v = acc[i][j][r];
        if (EPI == 1) v += aux[(long long)row * ldc + col];
        else if (EPI == 2) {
          float gv = aux[(long long)row * ldc + col];
          v *= gv / (1.0f + __expf(-gv));
        }
        C[(long long)row * ldc + col] = v;
      }
    }
  }
}

__global__ __launch_bounds__(256)
void rmsnorm_k(const float* __restrict__ x, const float* __restrict__ w, float* __restrict__ y)
{
  __shared__ float red[4];
  const int s = blockIdx.x, t = threadIdx.x;
  const float4* xr = (const float4*)(x + (long long)s * 4096);
  const float4* wr = (const float4*)w;
  float4* yr = (float4*)(y + (long long)s * 4096);
  float4 v[4];
  float ss = 0.f;
#pragma unroll
  for (int i = 0; i < 4; ++i) {
    v[i] = xr[t + i * 256];
    ss += v[i].x * v[i].x + v[i].y * v[i].y + v[i].z * v[i].z + v[i].w * v[i].w;
  }
  for (int o = 32; o; o >>= 1) ss += __shfl_xor(ss, o, 64);
  if ((t & 63) == 0) red[t >> 6] = ss;
  __syncthreads();
  float tot = red[0] + red[1] + red[2] + red[3];
  float inv = 1.0f / sqrtf(tot * (1.0f / 4096.0f) + 1e-6f);
#pragma unroll
  for (int i = 0; i < 4; ++i) {
    float4 wv = wr[t + i * 256];
    float4 o4;
    o4.x = v[i].x * inv * wv.x;
    o4.y = v[i].y * inv * wv.y;
    o4.z = v[i].z * inv * wv.z;
    o4.w = v[i].w * inv * wv.w;
    yr[t + i * 256] = o4;
  }
}

// qkv [1024,12288] -> roped q_r,k_r [head][s][128]; v transposed to v_t [head][128][1024]
__global__ __launch_bounds__(256)
void rope_k(const float* __restrict__ qkv, const int* __restrict__ pos,
            const float* __restrict__ cosT, const float* __restrict__ sinT,
            float* __restrict__ q_r, float* __restrict__ k_r, float* __restrict__ v_t)
{
  __shared__ float vs[64][129];
  const int h = blockIdx.x, s0 = blockIdx.y * 64, t = threadIdx.x;
  for (int i = 0; i < 32; ++i) {
    int idx = t + i * 256;
    int sl = idx >> 7, d = idx & 127;
    int s = s0 + sl;
    const float* rowp = qkv + (long long)s * 12288 + h * 128;
    float qv = rowp[d], kv = rowp[4096 + d], vv = rowp[8192 + d];
    float qp = (d < 64) ? -rowp[d + 64] : rowp[d - 64];
    float kp = (d < 64) ? -rowp[4096 + d + 64] : rowp[4096 + d - 64];
    int p = pos[s];
    float c = cosT[p * 128 + d], sn = sinT[p * 128 + d];
    long long o = ((long long)h * 1024 + s) * 128 + d;
    q_r[o] = qv * c + qp * sn;
    k_r[o] = kv * c + kp * sn;
    vs[sl][d] = vv;
  }
  __syncthreads();
  for (int i = 0; i < 32; ++i) {
    int idx = t + i * 256;
    int d = idx >> 6, sl = idx & 63;
    v_t[((long long)h * 128 + d) * 1024 + s0 + sl] = vs[sl][d];
  }
}

// causal softmax over row q (k <= q live, rest -> 0), scale folded in. One block per (q,h).
__global__ __launch_bounds__(256)
void softmax_causal_k(float* __restrict__ P, float scale)
{
  __shared__ float red[8];
  const int q = blockIdx.x, h = blockIdx.y, t = threadIdx.x;
  float* row = P + ((long long)h * 1024 + q) * 1024;
  const int n = q + 1;
  float vals[4];
  float mx = -3.0e38f;
#pragma unroll
  for (int i = 0; i < 4; ++i) {
    int k = t + i * 256;
    vals[i] = (k < n) ? row[k] * scale : -3.0e38f;
    mx = fmaxf(mx, vals[i]);
  }
  for (int o = 32; o; o >>= 1) mx = fmaxf(mx, __shfl_xor(mx, o, 64));
  if ((t & 63) == 0) red[t >> 6] = mx;
  __syncthreads();
  mx = fmaxf(fmaxf(red[0], red[1]), fmaxf(red[2], red[3]));
  float sum = 0.f;
#pragma unroll
  for (int i = 0; i < 4; ++i) {
    int k = t + i * 256;
    float e = (k < n) ? __expf(vals[i] - mx) : 0.f;
    vals[i] = e;
    sum += e;
  }
  for (int o = 32; o; o >>= 1) sum += __shfl_xor(sum, o, 64);
  if ((t & 63) == 0) red[4 + (t >> 6)] = sum;
  __syncthreads();
  float inv = 1.0f / (red[4] + red[5] + red[6] + red[7]);
#pragma unroll
  for (int i = 0; i < 4; ++i) row[t + i * 256] = vals[i] * inv;
}

extern "C" void kernel_launch(void* const* d_in, const int* in_sizes, int n_in,
                              void* d_out, int out_size, void* d_ws, size_t ws_size,
                              hipStream_t stream) {
  const float* x      = (const float*)d_in[0];
  const int*   pos    = (const int*)d_in[1];
  const float* qkv_w  = (const float*)d_in[2];
  const float* o_w    = (const float*)d_in[3];
  const float* gate_w = (const float*)d_in[4];
  const float* up_w   = (const float*)d_in[5];
  const float* down_w = (const float*)d_in[6];
  const float* ln1    = (const float*)d_in[7];
  const float* ln2    = (const float*)d_in[8];
  const float* cosT   = (const float*)d_in[9];
  const float* sinT   = (const float*)d_in[10];
  float* out = (float*)d_out;

  float* p = (float*)d_ws;
  float* y    = p; p += (long long)1024 * 4096;
  float* qkvb = p; p += (long long)1024 * 12288;
  float* q_r  = p; p += (long long)32 * 1024 * 128;
  float* k_r  = p; p += (long long)32 * 1024 * 128;
  float* v_t  = p; p += (long long)32 * 1024 * 128;
  float* Pb   = p; p += (long long)32 * 1024 * 1024;
  float* attn = p; p += (long long)1024 * 4096;
  float* hB   = p; p += (long long)1024 * 4096;
  float* hC   = p; p += (long long)1024 * 4096;
  float* g    = p; p += (long long)1024 * 11008;
  float* gu   = p; p += (long long)1024 * 11008;

  const float SCALE = 0.08838834764831843f;  // 1/sqrt(128)

  for (int L = 0; L < 2; ++L) {
    const float* h_in = (L == 0) ? x : hC;
    float* h_fin = (L == 1) ? out : hC;
    const float* qkvw = qkv_w + (long long)L * 12288 * 4096;
    const float* ow   = o_w   + (long long)L * 4096 * 4096;
    const float* gw   = gate_w + (long long)L * 11008 * 4096;
    const float* uw   = up_w  + (long long)L * 11008 * 4096;
    const float* dw   = down_w + (long long)L * 4096 * 11008;

    // y = rmsnorm(h_in, ln1)
    rmsnorm_k<<<dim3(1024), dim3(256), 0, stream>>>(h_in, ln1 + L * 4096, y);
    // qkv = y @ qkv_w^T  [1024,12288]
    gemm_bt<0, false><<<dim3(96, 8, 1), dim3(256), 0, stream>>>(
        y, qkvw, qkvb, nullptr, 4096, 4096, 4096, 12288, 0, 0, 0);
    // rope + head-split + V transpose
    rope_k<<<dim3(32, 16), dim3(256), 0, stream>>>(qkvb, pos, cosT, sinT, q_r, k_r, v_t);
    // scores[h] = q_r[h] @ k_r[h]^T  (causal blocks only)
    gemm_bt<0, true><<<dim3(8, 8, 32), dim3(256), 0, stream>>>(
        q_r, k_r, Pb, nullptr, 128, 128, 128, 1024,
        (long long)1024 * 128, (long long)1024 * 128, (long long)1024 * 1024);
    // causal softmax (in-place)
    softmax_causal_k<<<dim3(1024, 32), dim3(256), 0, stream>>>(Pb, SCALE);
    // attn[:, h*128:(h+1)*128] = P[h] @ v_t[h]^T
    gemm_bt<0, false><<<dim3(1, 8, 32), dim3(256), 0, stream>>>(
        Pb, v_t, attn, nullptr, 1024, 1024, 1024, 4096,
        (long long)1024 * 1024, (long long)128 * 1024, 128);
    // hB = h_in + attn @ o_w^T
    gemm_bt<1, false><<<dim3(32, 8, 1), dim3(256), 0, stream>>>(
        attn, ow, hB, h_in, 4096, 4096, 4096, 4096, 0, 0, 0);
    // y = rmsnorm(hB, ln2)
    rmsnorm_k<<<dim3(1024), dim3(256), 0, stream>>>(hB, ln2 + L * 4096, y);
    // g = y @ gate_w^T
    gemm_bt<0, false><<<dim3(86, 8, 1), dim3(256), 0, stream>>>(
        y, gw, g, nullptr, 4096, 4096, 4096, 11008, 0, 0, 0);
    // gu = silu(g) * (y @ up_w^T)
    gemm_bt<2, false><<<dim3(86, 8, 1), dim3(256), 0, stream>>>(
        y, uw, gu, g, 4096, 4096, 4096, 11008, 0, 0, 0);
    // h_fin = hB + gu @ down_w^T
    gemm_bt<1, false><<<dim3(32, 8, 1), dim3(256), 0, stream>>>(
        gu, dw, h_fin, hB, 11008, 11008, 11008, 4096, 0, 0, 0);
  }
}